// Round 2
// baseline (1080.044 us; speedup 1.0000x reference)
//
#include <hip/hip_runtime.h>
#include <hip/hip_bf16.h>

typedef __attribute__((ext_vector_type(8))) short short8;
typedef __attribute__((ext_vector_type(4))) float f32x4;
typedef unsigned short u16;
typedef unsigned int u32;

#define NTOK   8192
#define DMODEL 1024
#define DFF    4096
#define NEXP   8
#define NPAIR  (NTOK * 2)
#define BM     128
#define BN     64
#define BKC    64
#define MT     136            // ceil((16384 + 8*127)/128)
#define PPAD   (MT * BM)      // 17408

// ---- workspace layout (bytes) ----
#define OFF_XB   0ull
#define OFF_W1T  (OFF_XB  + (size_t)NTOK * DMODEL * 2)        //  16,777,216
#define OFF_W2T  (OFF_W1T + (size_t)NEXP * DFF * DMODEL * 2)  //  83,886,080
#define OFF_W3T  (OFF_W2T + (size_t)NEXP * DFF * DMODEL * 2)  // 150,994,944
#define OFF_H    (OFF_W3T + (size_t)NEXP * DMODEL * DFF * 2)  // 218,103,808
#define OFF_TOK  (OFF_H   + (size_t)PPAD * DFF * 2)           // 360,710,144
#define OFF_WGT  (OFF_TOK + (size_t)PPAD * 4)
#define OFF_CNT  (OFF_WGT + (size_t)PPAD * 4)
#define OFF_CUR  (OFF_CNT + 64)
#define OFF_OFFP (OFF_CUR + 64)
#define WS_END   (OFF_OFFP + 64)

#define GLOAD16(gp, lp)                                                        \
  __builtin_amdgcn_global_load_lds(                                            \
      (const __attribute__((address_space(1))) u32*)(gp),                      \
      (__attribute__((address_space(3))) u32*)(lp), 16, 0, 0)

__device__ __forceinline__ u16 f2bu(float f) {
  __hip_bfloat16 b = __float2bfloat16(f);
  return __builtin_bit_cast(u16, b);
}

// ---------------- conversion kernels ----------------

__global__ __launch_bounds__(256) void cvt_x_k(const float* __restrict__ x,
                                               u16* __restrict__ xb) {
  int i = blockIdx.x * 256 + threadIdx.x;            // 2M threads, 4 elems each
  float4 v = ((const float4*)x)[i];
  unsigned long long pk = (unsigned long long)f2bu(v.x) |
                          ((unsigned long long)f2bu(v.y) << 16) |
                          ((unsigned long long)f2bu(v.z) << 32) |
                          ((unsigned long long)f2bu(v.w) << 48);
  ((unsigned long long*)xb)[i] = pk;
}

// transpose [R][C] fp32 -> [C][R] bf16, batched over blockIdx.z
__global__ __launch_bounds__(256) void tr_cvt_k(const float* __restrict__ src,
                                                u16* __restrict__ dst, int R, int C) {
  src += (size_t)blockIdx.z * R * C;
  dst += (size_t)blockIdx.z * R * C;
  int c0 = blockIdx.x * 64, r0 = blockIdx.y * 64;
  __shared__ float tile[64][65];
  int tid = threadIdx.x;
  int f4 = tid & 15, rr = tid >> 4;
#pragma unroll
  for (int p = 0; p < 4; ++p) {
    int r = rr + p * 16;
    float4 v = *(const float4*)(src + (size_t)(r0 + r) * C + c0 + f4 * 4);
    tile[r][f4 * 4 + 0] = v.x; tile[r][f4 * 4 + 1] = v.y;
    tile[r][f4 * 4 + 2] = v.z; tile[r][f4 * 4 + 3] = v.w;
  }
  __syncthreads();
  int ch = tid & 7, cc = tid >> 3;
#pragma unroll
  for (int p = 0; p < 2; ++p) {
    int c = cc + p * 32;
    short8 s;
#pragma unroll
    for (int j = 0; j < 8; ++j) s[j] = (short)f2bu(tile[ch * 8 + j][c]);
    *(short8*)(dst + (size_t)(c0 + c) * R + r0 + ch * 8) = s;
  }
}

// ---------------- routing kernels ----------------

__global__ __launch_bounds__(256) void count_k(const int* __restrict__ ei,
                                               int* __restrict__ cnt) {
  int i = blockIdx.x * 256 + threadIdx.x;            // exactly NPAIR threads
  atomicAdd(&cnt[ei[i]], 1);
}

__global__ void scan_k(const int* __restrict__ cnt, int* __restrict__ offp) {
  if (threadIdx.x == 0) {
    int a = 0;
#pragma unroll
    for (int e = 0; e < NEXP; ++e) { offp[e] = a; a += (cnt[e] + BM - 1) & ~(BM - 1); }
    offp[NEXP] = a;
  }
}

__global__ __launch_bounds__(256) void scatter_k(const int* __restrict__ ei,
                                                 const float* __restrict__ ew,
                                                 const int* __restrict__ offp,
                                                 int* __restrict__ cur,
                                                 int* __restrict__ tok,
                                                 float* __restrict__ wg) {
  int i = blockIdx.x * 256 + threadIdx.x;
  int e = ei[i];
  int p = offp[e] + atomicAdd(&cur[e], 1);
  tok[p] = i >> 1;
  wg[p] = ew[i];
}

// ---------------- stage 1: h = silu(x@W1) * (x@W2), grouped ----------------
// Double-buffered LDS, single barrier per K-tile: next-tile global_load_lds is
// issued BEFORE the current tile's ds_read+MFMA; the trailing __syncthreads()
// (implicit vmcnt(0)+lgkmcnt(0) drain) both completes the prefetch and
// guarantees all waves finished reading cur before it is overwritten.

__global__ __launch_bounds__(256) void stage1_k(const u16* __restrict__ xb,
                                                const u16* __restrict__ w1t,
                                                const u16* __restrict__ w2t,
                                                u16* __restrict__ h,
                                                const int* __restrict__ tok,
                                                const int* __restrict__ offp) {
  __shared__ __align__(16) u16 As[2][BM * BKC];
  __shared__ __align__(16) u16 B1s[2][BN * BKC];
  __shared__ __align__(16) u16 B2s[2][BN * BKC];
  const int r0 = blockIdx.y * BM;
  if (r0 >= offp[NEXP]) return;
  int e = 0;
#pragma unroll
  for (int q = 0; q < 7; ++q) e += (offp[e + 1] <= r0) ? 1 : 0;
  const int n0 = blockIdx.x * BN;
  const int tid = threadIdx.x;
  const int lane = tid & 63, w = tid >> 6;
  const int wm = w >> 1, wn = w & 1;
  const int lr = lane >> 3, seg = lane & 7;

  // staging source pointers (source-side XOR swizzle, LDS dest linear)
  const u16* aga[4];
  int adst[4];
#pragma unroll
  for (int j = 0; j < 4; ++j) {
    int rowl = w * 32 + j * 8 + lr;
    int t = tok[r0 + rowl];
    aga[j] = xb + (size_t)t * DMODEL + ((seg ^ (rowl & 7)) << 3);
    adst[j] = (w * 32 + j * 8) * BKC;
  }
  const u16* w1e = w1t + (size_t)e * DFF * DMODEL;
  const u16* w2e = w2t + (size_t)e * DFF * DMODEL;
  const u16* bga1[2]; const u16* bga2[2];
  int bdst[2];
#pragma unroll
  for (int j = 0; j < 2; ++j) {
    int coll = w * 16 + j * 8 + lr;
    size_t ro = (size_t)(n0 + coll) * DMODEL + ((seg ^ (coll & 7)) << 3);
    bga1[j] = w1e + ro; bga2[j] = w2e + ro;
    bdst[j] = (w * 16 + j * 8) * BKC;
  }

#define S1_STAGE(b, ko)                                                        \
  do {                                                                         \
    _Pragma("unroll")                                                          \
    for (int j = 0; j < 4; ++j) GLOAD16(aga[j] + (ko), &As[b][adst[j]]);       \
    _Pragma("unroll")                                                          \
    for (int j = 0; j < 2; ++j) {                                              \
      GLOAD16(bga1[j] + (ko), &B1s[b][bdst[j]]);                               \
      GLOAD16(bga2[j] + (ko), &B2s[b][bdst[j]]);                               \
    }                                                                          \
  } while (0)

  int aoff[4][2], boff[2][2];
  {
    int ar = wm * 64 + (lane & 15), ks = lane >> 4;
#pragma unroll
    for (int mi = 0; mi < 4; ++mi)
#pragma unroll
      for (int kk = 0; kk < 2; ++kk) {
        int row = ar + mi * 16;
        aoff[mi][kk] = row * BKC + (((kk * 4 + ks) ^ (row & 7)) << 3);
      }
    int bc = wn * 32 + (lane & 15);
#pragma unroll
    for (int ni = 0; ni < 2; ++ni)
#pragma unroll
      for (int kk = 0; kk < 2; ++kk) {
        int col = bc + ni * 16;
        boff[ni][kk] = col * BKC + (((kk * 4 + ks) ^ (col & 7)) << 3);
      }
  }

  f32x4 accg[4][2], accv[4][2];
  const f32x4 zero = {0.f, 0.f, 0.f, 0.f};
#pragma unroll
  for (int mi = 0; mi < 4; ++mi)
#pragma unroll
    for (int ni = 0; ni < 2; ++ni) { accg[mi][ni] = zero; accv[mi][ni] = zero; }

  S1_STAGE(0, 0);
  __syncthreads();
  int cur = 0;
  const int NK = DMODEL / BKC;
  for (int kc = 0; kc < NK; ++kc) {
    if (kc + 1 < NK) S1_STAGE(cur ^ 1, (kc + 1) * BKC);
    const u16* Ac  = As[cur];
    const u16* B1c = B1s[cur];
    const u16* B2c = B2s[cur];
#pragma unroll
    for (int kk = 0; kk < 2; ++kk) {
      short8 a[4], b1[2], b2[2];
#pragma unroll
      for (int mi = 0; mi < 4; ++mi) a[mi] = *(const short8*)(Ac + aoff[mi][kk]);
#pragma unroll
      for (int ni = 0; ni < 2; ++ni) { b1[ni] = *(const short8*)(B1c + boff[ni][kk]);
                                       b2[ni] = *(const short8*)(B2c + boff[ni][kk]); }
#pragma unroll
      for (int mi = 0; mi < 4; ++mi)
#pragma unroll
        for (int ni = 0; ni < 2; ++ni) {
          accg[mi][ni] = __builtin_amdgcn_mfma_f32_16x16x32_bf16(a[mi], b1[ni], accg[mi][ni], 0, 0, 0);
          accv[mi][ni] = __builtin_amdgcn_mfma_f32_16x16x32_bf16(a[mi], b2[ni], accv[mi][ni], 0, 0, 0);
        }
    }
    __syncthreads();
    cur ^= 1;
  }

  const int prow = r0 + wm * 64 + ((lane >> 4) << 2);
  const int pcol = n0 + wn * 32 + (lane & 15);
#pragma unroll
  for (int mi = 0; mi < 4; ++mi)
#pragma unroll
    for (int ni = 0; ni < 2; ++ni)
#pragma unroll
      for (int j = 0; j < 4; ++j) {
        float g = accg[mi][ni][j];
        float v = accv[mi][ni][j];
        float s = g / (1.f + __expf(-g));       // silu(g)
        h[(size_t)(prow + mi * 16 + j) * DFF + (pcol + ni * 16)] = f2bu(s * v);
      }
}

// ---------------- stage 2: out += p * (h @ W3), grouped ----------------

__global__ __launch_bounds__(256) void stage2_k(const u16* __restrict__ h,
                                                const u16* __restrict__ w3t,
                                                float* __restrict__ out,
                                                const int* __restrict__ tok,
                                                const float* __restrict__ wg,
                                                const int* __restrict__ offp) {
  __shared__ __align__(16) u16 As[2][BM * BKC];
  __shared__ __align__(16) u16 Bs[2][BN * BKC];
  const int r0 = blockIdx.y * BM;
  if (r0 >= offp[NEXP]) return;
  int e = 0;
#pragma unroll
  for (int q = 0; q < 7; ++q) e += (offp[e + 1] <= r0) ? 1 : 0;
  const int n0 = blockIdx.x * BN;
  const int tid = threadIdx.x;
  const int lane = tid & 63, w = tid >> 6;
  const int wm = w >> 1, wn = w & 1;
  const int lr = lane >> 3, seg = lane & 7;

  const u16* aga[4];
  int adst[4];
#pragma unroll
  for (int j = 0; j < 4; ++j) {
    int rowl = w * 32 + j * 8 + lr;
    aga[j] = h + (size_t)(r0 + rowl) * DFF + ((seg ^ (rowl & 7)) << 3);
    adst[j] = (w * 32 + j * 8) * BKC;
  }
  const u16* w3e = w3t + (size_t)e * DMODEL * DFF;
  const u16* bga[2];
  int bdst[2];
#pragma unroll
  for (int j = 0; j < 2; ++j) {
    int coll = w * 16 + j * 8 + lr;
    bga[j] = w3e + (size_t)(n0 + coll) * DFF + ((seg ^ (coll & 7)) << 3);
    bdst[j] = (w * 16 + j * 8) * BKC;
  }

#define S2_STAGE(b, ko)                                                        \
  do {                                                                         \
    _Pragma("unroll")                                                          \
    for (int j = 0; j < 4; ++j) GLOAD16(aga[j] + (ko), &As[b][adst[j]]);       \
    _Pragma("unroll")                                                          \
    for (int j = 0; j < 2; ++j) GLOAD16(bga[j] + (ko), &Bs[b][bdst[j]]);       \
  } while (0)

  int aoff[4][2], boff[2][2];
  {
    int ar = wm * 64 + (lane & 15), ks = lane >> 4;
#pragma unroll
    for (int mi = 0; mi < 4; ++mi)
#pragma unroll
      for (int kk = 0; kk < 2; ++kk) {
        int row = ar + mi * 16;
        aoff[mi][kk] = row * BKC + (((kk * 4 + ks) ^ (row & 7)) << 3);
      }
    int bc = wn * 32 + (lane & 15);
#pragma unroll
    for (int ni = 0; ni < 2; ++ni)
#pragma unroll
      for (int kk = 0; kk < 2; ++kk) {
        int col = bc + ni * 16;
        boff[ni][kk] = col * BKC + (((kk * 4 + ks) ^ (col & 7)) << 3);
      }
  }

  f32x4 acc[4][2];
  const f32x4 zero = {0.f, 0.f, 0.f, 0.f};
#pragma unroll
  for (int mi = 0; mi < 4; ++mi)
#pragma unroll
    for (int ni = 0; ni < 2; ++ni) acc[mi][ni] = zero;

  S2_STAGE(0, 0);
  __syncthreads();
  int cur = 0;
  const int NK = DFF / BKC;
  for (int kc = 0; kc < NK; ++kc) {
    if (kc + 1 < NK) S2_STAGE(cur ^ 1, (kc + 1) * BKC);
    const u16* Ac = As[cur];
    const u16* Bc = Bs[cur];
#pragma unroll
    for (int kk = 0; kk < 2; ++kk) {
      short8 a[4], b[2];
#pragma unroll
      for (int mi = 0; mi < 4; ++mi) a[mi] = *(const short8*)(Ac + aoff[mi][kk]);
#pragma unroll
      for (int ni = 0; ni < 2; ++ni) b[ni] = *(const short8*)(Bc + boff[ni][kk]);
#pragma unroll
      for (int mi = 0; mi < 4; ++mi)
#pragma unroll
        for (int ni = 0; ni < 2; ++ni)
          acc[mi][ni] = __builtin_amdgcn_mfma_f32_16x16x32_bf16(a[mi], b[ni], acc[mi][ni], 0, 0, 0);
    }
    __syncthreads();
    cur ^= 1;
  }

  const int prow = r0 + wm * 64 + ((lane >> 4) << 2);
  const int pcol = n0 + wn * 32 + (lane & 15);
#pragma unroll
  for (int mi = 0; mi < 4; ++mi)
#pragma unroll
    for (int j = 0; j < 4; ++j) {
      int pos = prow + mi * 16 + j;
      float p = wg[pos];
      if (p != 0.f) {
        int t = tok[pos];
#pragma unroll
        for (int ni = 0; ni < 2; ++ni)
          atomicAdd(&out[(size_t)t * DMODEL + pcol + ni * 16], p * acc[mi][ni][j]);
      }
    }
}

// ---------------- launch ----------------

extern "C" void kernel_launch(void* const* d_in, const int* in_sizes, int n_in,
                              void* d_out, int out_size, void* d_ws, size_t ws_size,
                              hipStream_t stream) {
  (void)in_sizes; (void)n_in;
  const float* x  = (const float*)d_in[0];
  const int*   ei = (const int*)d_in[1];
  const float* ew = (const float*)d_in[2];
  const float* w1 = (const float*)d_in[3];
  const float* w2 = (const float*)d_in[4];
  const float* w3 = (const float*)d_in[5];
  float* out = (float*)d_out;
  char* ws = (char*)d_ws;

  hipMemsetAsync(out, 0, (size_t)out_size * sizeof(float), stream);
  if (ws_size < WS_END) return;   // ws too small: leave zeros (diagnosable absmax)

  u16* xb   = (u16*)(ws + OFF_XB);
  u16* w1t  = (u16*)(ws + OFF_W1T);
  u16* w2t  = (u16*)(ws + OFF_W2T);
  u16* w3t  = (u16*)(ws + OFF_W3T);
  u16* hb   = (u16*)(ws + OFF_H);
  int* tok  = (int*)(ws + OFF_TOK);
  float* wg = (float*)(ws + OFF_WGT);
  int* cnt  = (int*)(ws + OFF_CNT);
  int* cur  = (int*)(ws + OFF_CUR);
  int* offp = (int*)(ws + OFF_OFFP);

  hipMemsetAsync(ws + OFF_TOK, 0, (size_t)(WS_END - OFF_TOK), stream);

  cvt_x_k<<<dim3(NTOK * DMODEL / 4 / 256), 256, 0, stream>>>(x, xb);
  tr_cvt_k<<<dim3(DFF / 64, DMODEL / 64, NEXP), 256, 0, stream>>>(w1, w1t, DMODEL, DFF);
  tr_cvt_k<<<dim3(DFF / 64, DMODEL / 64, NEXP), 256, 0, stream>>>(w2, w2t, DMODEL, DFF);
  tr_cvt_k<<<dim3(DMODEL / 64, DFF / 64, NEXP), 256, 0, stream>>>(w3, w3t, DFF, DMODEL);
  count_k<<<dim3(NPAIR / 256), 256, 0, stream>>>(ei, cnt);
  scan_k<<<1, 64, 0, stream>>>(cnt, offp);
  scatter_k<<<dim3(NPAIR / 256), 256, 0, stream>>>(ei, ew, offp, cur, tok, wg);
  stage1_k<<<dim3(DFF / BN, MT), 256, 0, stream>>>(xb, w1t, w2t, hb, tok, offp);
  stage2_k<<<dim3(DMODEL / BN, MT), 256, 0, stream>>>(hb, w3t, out, tok, wg, offp);
}

// Round 3
// 866.435 us; speedup vs baseline: 1.2465x; 1.2465x over previous
//
#include <hip/hip_runtime.h>
#include <hip/hip_bf16.h>

typedef __attribute__((ext_vector_type(8))) short short8;
typedef __attribute__((ext_vector_type(4))) float f32x4;
typedef unsigned short u16;
typedef unsigned int u32;

#define NTOK   8192
#define DMODEL 1024
#define DFF    4096
#define NEXP   8
#define NPAIR  (NTOK * 2)
#define PADM   256            // per-expert padding (stage1 tile M)
#define MT1    72             // ceil((16384 + 8*255)/256)
#define PPAD   (MT1 * PADM)   // 18432
#define MT2    (PPAD / 128)   // 144 stage2 M-tiles

// ---- workspace layout (bytes) ----
#define OFF_XB   0ull
#define OFF_W1T  (OFF_XB  + (size_t)NTOK * DMODEL * 2)        //  16,777,216
#define OFF_W2T  (OFF_W1T + (size_t)NEXP * DFF * DMODEL * 2)  //  83,886,080
#define OFF_W3T  (OFF_W2T + (size_t)NEXP * DFF * DMODEL * 2)  // 150,994,944
#define OFF_H    (OFF_W3T + (size_t)NEXP * DMODEL * DFF * 2)  // 218,103,808
#define OFF_TOK  (OFF_H   + (size_t)PPAD * DFF * 2)           // 369,098,752
#define OFF_WGT  (OFF_TOK + (size_t)PPAD * 4)
#define OFF_CNT  (OFF_WGT + (size_t)PPAD * 4)
#define OFF_CUR  (OFF_CNT + 64)
#define OFF_OFFP (OFF_CUR + 64)
#define WS_END   (OFF_OFFP + 64)

#define GLOAD16(gp, lp)                                                        \
  __builtin_amdgcn_global_load_lds(                                            \
      (const __attribute__((address_space(1))) u32*)(gp),                      \
      (__attribute__((address_space(3))) u32*)(lp), 16, 0, 0)

__device__ __forceinline__ u16 f2bu(float f) {
  __hip_bfloat16 b = __float2bfloat16(f);
  return __builtin_bit_cast(u16, b);
}

// ---------------- conversion kernels ----------------

__global__ __launch_bounds__(256) void cvt_x_k(const float* __restrict__ x,
                                               u16* __restrict__ xb) {
  int i = blockIdx.x * 256 + threadIdx.x;
  float4 v = ((const float4*)x)[i];
  unsigned long long pk = (unsigned long long)f2bu(v.x) |
                          ((unsigned long long)f2bu(v.y) << 16) |
                          ((unsigned long long)f2bu(v.z) << 32) |
                          ((unsigned long long)f2bu(v.w) << 48);
  ((unsigned long long*)xb)[i] = pk;
}

// transpose [R][C] fp32 -> [C][R] bf16, batched over blockIdx.z
__global__ __launch_bounds__(256) void tr_cvt_k(const float* __restrict__ src,
                                                u16* __restrict__ dst, int R, int C) {
  src += (size_t)blockIdx.z * R * C;
  dst += (size_t)blockIdx.z * R * C;
  int c0 = blockIdx.x * 64, r0 = blockIdx.y * 64;
  __shared__ float tile[64][65];
  int tid = threadIdx.x;
  int f4 = tid & 15, rr = tid >> 4;
#pragma unroll
  for (int p = 0; p < 4; ++p) {
    int r = rr + p * 16;
    float4 v = *(const float4*)(src + (size_t)(r0 + r) * C + c0 + f4 * 4);
    tile[r][f4 * 4 + 0] = v.x; tile[r][f4 * 4 + 1] = v.y;
    tile[r][f4 * 4 + 2] = v.z; tile[r][f4 * 4 + 3] = v.w;
  }
  __syncthreads();
  int ch = tid & 7, cc = tid >> 3;
#pragma unroll
  for (int p = 0; p < 2; ++p) {
    int c = cc + p * 32;
    short8 s;
#pragma unroll
    for (int j = 0; j < 8; ++j) s[j] = (short)f2bu(tile[ch * 8 + j][c]);
    *(short8*)(dst + (size_t)(c0 + c) * R + r0 + ch * 8) = s;
  }
}

// ---------------- routing kernels ----------------

__global__ __launch_bounds__(256) void count_k(const int* __restrict__ ei,
                                               int* __restrict__ cnt) {
  int i = blockIdx.x * 256 + threadIdx.x;
  atomicAdd(&cnt[ei[i]], 1);
}

__global__ void scan_k(const int* __restrict__ cnt, int* __restrict__ offp) {
  if (threadIdx.x == 0) {
    int a = 0;
#pragma unroll
    for (int e = 0; e < NEXP; ++e) { offp[e] = a; a += (cnt[e] + PADM - 1) & ~(PADM - 1); }
    offp[NEXP] = a;
  }
}

__global__ __launch_bounds__(256) void scatter_k(const int* __restrict__ ei,
                                                 const float* __restrict__ ew,
                                                 const int* __restrict__ offp,
                                                 int* __restrict__ cur,
                                                 int* __restrict__ tok,
                                                 float* __restrict__ wg) {
  int i = blockIdx.x * 256 + threadIdx.x;
  int e = ei[i];
  int p = offp[e] + atomicAdd(&cur[e], 1);
  tok[p] = i >> 1;
  wg[p] = ew[i];
}

// ---------------- stage 1: h = silu(x@W1) * (x@W2), grouped ----------------
// 8-phase-style schedule: 512 thr (8 waves, 2M x 4N), tile 256 x (128|128),
// BK=64, dbuf LDS 128KB, raw s_barrier per phase, setprio around MFMA
// clusters, single vmcnt(0) drain per K-step (loads issued 1-4 phases prior).

#define A_STR 16384   // u16 per A buffer (256*64)
#define B_STR 8192    // u16 per B buffer (128*64)

__global__ __launch_bounds__(512, 2) void stage1_k(const u16* __restrict__ xb,
                                                   const u16* __restrict__ w1t,
                                                   const u16* __restrict__ w2t,
                                                   u16* __restrict__ h,
                                                   const int* __restrict__ tok,
                                                   const int* __restrict__ offp) {
  extern __shared__ __align__(16) u16 lds[];   // [2*A | 2*B1 | 2*B2] = 131072 B
  const int r0 = blockIdx.y * PADM;
  if (r0 >= offp[NEXP]) return;
  int e = 0;
#pragma unroll
  for (int q = 0; q < 7; ++q) e += (offp[e + 1] <= r0) ? 1 : 0;
  const int n0 = blockIdx.x * 128;
  const int tid = threadIdx.x;
  const int lane = tid & 63, w = tid >> 6;
  const int wm = w >> 2, wn = w & 3;
  const int lr = lane >> 3, seg = lane & 7;

  // ---- staging source pointers (per-lane, source-side XOR swizzle) ----
  const u16* aga[4];
  int adb[4];
#pragma unroll
  for (int u = 0; u < 2; ++u)
#pragma unroll
    for (int j = 0; j < 2; ++j) {
      int row = u * 128 + w * 16 + j * 8 + lr;
      int t = tok[r0 + row];
      aga[u * 2 + j] = xb + (size_t)t * DMODEL + ((seg ^ (row & 7)) << 3);
      adb[u * 2 + j] = (u * 128 + w * 16 + j * 8) * 64;
    }
  const u16* w1e = w1t + (size_t)e * DFF * DMODEL;
  const u16* w2e = w2t + (size_t)e * DFF * DMODEL;
  const u16* bg1[2]; const u16* bg2[2];
  int bdb[2];
#pragma unroll
  for (int j = 0; j < 2; ++j) {
    int row = w * 16 + j * 8 + lr;               // B tile row = ff-col offset
    size_t ro = (size_t)(n0 + row) * DMODEL + ((seg ^ (row & 7)) << 3);
    bg1[j] = w1e + ro; bg2[j] = w2e + ro;
    bdb[j] = (w * 16 + j * 8) * 64;
  }

  // ---- fragment read offsets (u16 idx; kk=1 = kk=0 XOR 32) ----
  int aoff[8], boff[2];
  {
    int ks = lane >> 4;
#pragma unroll
    for (int mi = 0; mi < 8; ++mi) {
      int row = wm * 128 + mi * 16 + (lane & 15);
      aoff[mi] = row * 64 + ((ks ^ (row & 7)) << 3);
    }
#pragma unroll
    for (int ni = 0; ni < 2; ++ni) {
      int col = wn * 32 + ni * 16 + (lane & 15);
      boff[ni] = col * 64 + ((ks ^ (col & 7)) << 3);
    }
  }

  f32x4 accg[8][2], accv[8][2];
  const f32x4 zero = {0.f, 0.f, 0.f, 0.f};
#pragma unroll
  for (int mi = 0; mi < 8; ++mi)
#pragma unroll
    for (int ni = 0; ni < 2; ++ni) { accg[mi][ni] = zero; accv[mi][ni] = zero; }

  short8 af[4][2], bf1[2][2], bf2[2][2];

  // ---- prologue: stage K-step 0 into buffer 0 ----
  {
    u16* Aq = lds; u16* B1q = lds + 2 * A_STR; u16* B2q = lds + 2 * A_STR + 2 * B_STR;
#pragma unroll
    for (int j = 0; j < 4; ++j) GLOAD16(aga[j], Aq + adb[j]);
#pragma unroll
    for (int j = 0; j < 2; ++j) { GLOAD16(bg1[j], B1q + bdb[j]);
                                  GLOAD16(bg2[j], B2q + bdb[j]); }
    asm volatile("s_waitcnt vmcnt(0)" ::: "memory");
    __builtin_amdgcn_s_barrier();
    __builtin_amdgcn_sched_barrier(0);
  }

#define S1_STEP(P, KC)                                                         \
  {                                                                            \
    const u16* Ab  = lds + (P) * A_STR;                                        \
    const u16* B1b = lds + 2 * A_STR + (P) * B_STR;                            \
    const u16* B2b = lds + 2 * A_STR + 2 * B_STR + (P) * B_STR;                \
    u16* Aq  = lds + (1 - (P)) * A_STR;                                        \
    u16* B1q = lds + 2 * A_STR + (1 - (P)) * B_STR;                            \
    u16* B2q = lds + 2 * A_STR + 2 * B_STR + (1 - (P)) * B_STR;                \
    const int st = (KC) + 1 < 16;                                              \
    const int ko = ((KC) + 1) * 64;                                            \
    /* ---- P0: read a[0:3], b1; stage A half0; mfma accg[0:3] ---- */         \
    _Pragma("unroll") for (int mi = 0; mi < 4; ++mi)                           \
      _Pragma("unroll") for (int kk = 0; kk < 2; ++kk)                         \
        af[mi][kk] = *(const short8*)(Ab + (aoff[mi] ^ (kk << 5)));            \
    _Pragma("unroll") for (int ni = 0; ni < 2; ++ni)                           \
      _Pragma("unroll") for (int kk = 0; kk < 2; ++kk)                         \
        bf1[ni][kk] = *(const short8*)(B1b + (boff[ni] ^ (kk << 5)));          \
    if (st) { GLOAD16(aga[0] + ko, Aq + adb[0]);                               \
              GLOAD16(aga[1] + ko, Aq + adb[1]); }                             \
    __builtin_amdgcn_s_barrier();                                              \
    __builtin_amdgcn_s_setprio(1);                                             \
    _Pragma("unroll") for (int mi = 0; mi < 4; ++mi)                           \
      _Pragma("unroll") for (int ni = 0; ni < 2; ++ni)                         \
        _Pragma("unroll") for (int kk = 0; kk < 2; ++kk)                       \
          accg[mi][ni] = __builtin_amdgcn_mfma_f32_16x16x32_bf16(              \
              af[mi][kk], bf1[ni][kk], accg[mi][ni], 0, 0, 0);                 \
    __builtin_amdgcn_s_setprio(0);                                             \
    __builtin_amdgcn_s_barrier();                                              \
    /* ---- P1: read b2; stage A half1; mfma accv[0:3] ---- */                 \
    _Pragma("unroll") for (int ni = 0; ni < 2; ++ni)                           \
      _Pragma("unroll") for (int kk = 0; kk < 2; ++kk)                         \
        bf2[ni][kk] = *(const short8*)(B2b + (boff[ni] ^ (kk << 5)));          \
    if (st) { GLOAD16(aga[2] + ko, Aq + adb[2]);                               \
              GLOAD16(aga[3] + ko, Aq + adb[3]); }                             \
    __builtin_amdgcn_s_barrier();                                              \
    __builtin_amdgcn_s_setprio(1);                                             \
    _Pragma("unroll") for (int mi = 0; mi < 4; ++mi)                           \
      _Pragma("unroll") for (int ni = 0; ni < 2; ++ni)                         \
        _Pragma("unroll") for (int kk = 0; kk < 2; ++kk)                       \
          accv[mi][ni] = __builtin_amdgcn_mfma_f32_16x16x32_bf16(              \
              af[mi][kk], bf2[ni][kk], accv[mi][ni], 0, 0, 0);                 \
    __builtin_amdgcn_s_setprio(0);                                             \
    __builtin_amdgcn_s_barrier();                                              \
    /* ---- P2: read a[4:7]; stage B1; mfma accg[4:7] ---- */                  \
    _Pragma("unroll") for (int mi = 0; mi < 4; ++mi)                           \
      _Pragma("unroll") for (int kk = 0; kk < 2; ++kk)                         \
        af[mi][kk] = *(const short8*)(Ab + (aoff[4 + mi] ^ (kk << 5)));        \
    if (st) { GLOAD16(bg1[0] + ko, B1q + bdb[0]);                              \
              GLOAD16(bg1[1] + ko, B1q + bdb[1]); }                            \
    __builtin_amdgcn_s_barrier();                                              \
    __builtin_amdgcn_s_setprio(1);                                             \
    _Pragma("unroll") for (int mi = 0; mi < 4; ++mi)                           \
      _Pragma("unroll") for (int ni = 0; ni < 2; ++ni)                         \
        _Pragma("unroll") for (int kk = 0; kk < 2; ++kk)                       \
          accg[4 + mi][ni] = __builtin_amdgcn_mfma_f32_16x16x32_bf16(          \
              af[mi][kk], bf1[ni][kk], accg[4 + mi][ni], 0, 0, 0);             \
    __builtin_amdgcn_s_setprio(0);                                             \
    __builtin_amdgcn_s_barrier();                                              \
    /* ---- P3: stage B2; mfma accv[4:7]; end-of-step drain ---- */            \
    if (st) { GLOAD16(bg2[0] + ko, B2q + bdb[0]);                              \
              GLOAD16(bg2[1] + ko, B2q + bdb[1]); }                            \
    __builtin_amdgcn_s_barrier();                                              \
    __builtin_amdgcn_s_setprio(1);                                             \
    _Pragma("unroll") for (int mi = 0; mi < 4; ++mi)                           \
      _Pragma("unroll") for (int ni = 0; ni < 2; ++ni)                         \
        _Pragma("unroll") for (int kk = 0; kk < 2; ++kk)                       \
          accv[4 + mi][ni] = __builtin_amdgcn_mfma_f32_16x16x32_bf16(          \
              af[mi][kk], bf2[ni][kk], accv[4 + mi][ni], 0, 0, 0);             \
    __builtin_amdgcn_s_setprio(0);                                             \
    asm volatile("s_waitcnt vmcnt(0)" ::: "memory");                           \
    __builtin_amdgcn_s_barrier();                                              \
    __builtin_amdgcn_sched_barrier(0);                                         \
  }

  for (int kc = 0; kc < 16; kc += 2) {
    S1_STEP(0, kc)
    S1_STEP(1, kc + 1)
  }
#undef S1_STEP

  // ---- epilogue: silu(gate) * val -> h ----
  const int prow = r0 + wm * 128 + ((lane >> 4) << 2);
  const int pcol = n0 + wn * 32 + (lane & 15);
#pragma unroll
  for (int mi = 0; mi < 8; ++mi)
#pragma unroll
    for (int ni = 0; ni < 2; ++ni)
#pragma unroll
      for (int j = 0; j < 4; ++j) {
        float g = accg[mi][ni][j];
        float v = accv[mi][ni][j];
        float s = g / (1.f + __expf(-g));
        h[(size_t)(prow + mi * 16 + j) * DFF + (pcol + ni * 16)] = f2bu(s * v);
      }
}

// ---------------- stage 2: out += p * (h @ W3), grouped ----------------
// round-1 structure (known good): 256 thr, 128x64 tile, single-buffered LDS.

__global__ __launch_bounds__(256) void stage2_k(const u16* __restrict__ h,
                                                const u16* __restrict__ w3t,
                                                float* __restrict__ out,
                                                const int* __restrict__ tok,
                                                const float* __restrict__ wg,
                                                const int* __restrict__ offp) {
  __shared__ __align__(16) u16 As[128 * 64];
  __shared__ __align__(16) u16 Bs[64 * 64];
  const int r0 = blockIdx.y * 128;
  if (r0 >= offp[NEXP]) return;
  int e = 0;
#pragma unroll
  for (int q = 0; q < 7; ++q) e += (offp[e + 1] <= r0) ? 1 : 0;
  const int n0 = blockIdx.x * 64;
  const int tid = threadIdx.x;
  const int lane = tid & 63, w = tid >> 6;
  const int wm = w >> 1, wn = w & 1;
  const int lr = lane >> 3, seg = lane & 7;

  const u16* aga[4];
#pragma unroll
  for (int j = 0; j < 4; ++j) {
    int rowl = w * 32 + j * 8 + lr;
    aga[j] = h + (size_t)(r0 + rowl) * DFF + ((seg ^ (rowl & 7)) << 3);
  }
  const u16* w3e = w3t + (size_t)e * DMODEL * DFF;
  const u16* bga[2];
#pragma unroll
  for (int j = 0; j < 2; ++j) {
    int coll = w * 16 + j * 8 + lr;
    bga[j] = w3e + (size_t)(n0 + coll) * DFF + ((seg ^ (coll & 7)) << 3);
  }
  u16 *Ad[4], *Bd[2];
#pragma unroll
  for (int j = 0; j < 4; ++j) Ad[j] = As + (w * 32 + j * 8) * 64;
#pragma unroll
  for (int j = 0; j < 2; ++j) Bd[j] = Bs + (w * 16 + j * 8) * 64;

  int aoff[4][2], boff[2][2];
  {
    int ar = wm * 64 + (lane & 15), ks = lane >> 4;
#pragma unroll
    for (int mi = 0; mi < 4; ++mi)
#pragma unroll
      for (int kk = 0; kk < 2; ++kk) {
        int row = ar + mi * 16;
        aoff[mi][kk] = row * 64 + (((kk * 4 + ks) ^ (row & 7)) << 3);
      }
    int bc = wn * 32 + (lane & 15);
#pragma unroll
    for (int ni = 0; ni < 2; ++ni)
#pragma unroll
      for (int kk = 0; kk < 2; ++kk) {
        int col = bc + ni * 16;
        boff[ni][kk] = col * 64 + (((kk * 4 + ks) ^ (col & 7)) << 3);
      }
  }

  f32x4 acc[4][2];
  const f32x4 zero = {0.f, 0.f, 0.f, 0.f};
#pragma unroll
  for (int mi = 0; mi < 4; ++mi)
#pragma unroll
    for (int ni = 0; ni < 2; ++ni) acc[mi][ni] = zero;

  for (int kc = 0; kc < DFF / 64; ++kc) {
    const int ko = kc * 64;
#pragma unroll
    for (int j = 0; j < 4; ++j) GLOAD16(aga[j] + ko, Ad[j]);
#pragma unroll
    for (int j = 0; j < 2; ++j) GLOAD16(bga[j] + ko, Bd[j]);
    __syncthreads();
#pragma unroll
    for (int kk = 0; kk < 2; ++kk) {
      short8 a[4], b[2];
#pragma unroll
      for (int mi = 0; mi < 4; ++mi) a[mi] = *(const short8*)(As + aoff[mi][kk]);
#pragma unroll
      for (int ni = 0; ni < 2; ++ni) b[ni] = *(const short8*)(Bs + boff[ni][kk]);
#pragma unroll
      for (int mi = 0; mi < 4; ++mi)
#pragma unroll
        for (int ni = 0; ni < 2; ++ni)
          acc[mi][ni] = __builtin_amdgcn_mfma_f32_16x16x32_bf16(a[mi], b[ni], acc[mi][ni], 0, 0, 0);
    }
    __syncthreads();
  }

  const int prow = r0 + wm * 64 + ((lane >> 4) << 2);
  const int pcol = n0 + wn * 32 + (lane & 15);
#pragma unroll
  for (int mi = 0; mi < 4; ++mi)
#pragma unroll
    for (int j = 0; j < 4; ++j) {
      int pos = prow + mi * 16 + j;
      float p = wg[pos];
      if (p != 0.f) {
        int t = tok[pos];
#pragma unroll
        for (int ni = 0; ni < 2; ++ni)
          atomicAdd(&out[(size_t)t * DMODEL + pcol + ni * 16], p * acc[mi][ni][j]);
      }
    }
}

// ---------------- launch ----------------

extern "C" void kernel_launch(void* const* d_in, const int* in_sizes, int n_in,
                              void* d_out, int out_size, void* d_ws, size_t ws_size,
                              hipStream_t stream) {
  (void)in_sizes; (void)n_in;
  const float* x  = (const float*)d_in[0];
  const int*   ei = (const int*)d_in[1];
  const float* ew = (const float*)d_in[2];
  const float* w1 = (const float*)d_in[3];
  const float* w2 = (const float*)d_in[4];
  const float* w3 = (const float*)d_in[5];
  float* out = (float*)d_out;
  char* ws = (char*)d_ws;

  hipMemsetAsync(out, 0, (size_t)out_size * sizeof(float), stream);
  if (ws_size < WS_END) return;   // ws too small: leave zeros (diagnosable absmax)

  u16* xb   = (u16*)(ws + OFF_XB);
  u16* w1t  = (u16*)(ws + OFF_W1T);
  u16* w2t  = (u16*)(ws + OFF_W2T);
  u16* w3t  = (u16*)(ws + OFF_W3T);
  u16* hb   = (u16*)(ws + OFF_H);
  int* tok  = (int*)(ws + OFF_TOK);
  float* wg = (float*)(ws + OFF_WGT);
  int* cnt  = (int*)(ws + OFF_CNT);
  int* cur  = (int*)(ws + OFF_CUR);
  int* offp = (int*)(ws + OFF_OFFP);

  hipMemsetAsync(ws + OFF_TOK, 0, (size_t)(WS_END - OFF_TOK), stream);

  static int lds_attr_set = 0;
  (void)lds_attr_set;
  hipFuncSetAttribute(reinterpret_cast<const void*>(stage1_k),
                      hipFuncAttributeMaxDynamicSharedMemorySize, 131072);

  cvt_x_k<<<dim3(NTOK * DMODEL / 4 / 256), 256, 0, stream>>>(x, xb);
  tr_cvt_k<<<dim3(DFF / 64, DMODEL / 64, NEXP), 256, 0, stream>>>(w1, w1t, DMODEL, DFF);
  tr_cvt_k<<<dim3(DFF / 64, DMODEL / 64, NEXP), 256, 0, stream>>>(w2, w2t, DMODEL, DFF);
  tr_cvt_k<<<dim3(DMODEL / 64, DFF / 64, NEXP), 256, 0, stream>>>(w3, w3t, DFF, DMODEL);
  count_k<<<dim3(NPAIR / 256), 256, 0, stream>>>(ei, cnt);
  scan_k<<<1, 64, 0, stream>>>(cnt, offp);
  scatter_k<<<dim3(NPAIR / 256), 256, 0, stream>>>(ei, ew, offp, cur, tok, wg);
  stage1_k<<<dim3(DFF / 128, MT1), 512, 131072, stream>>>(xb, w1t, w2t, hb, tok, offp);
  stage2_k<<<dim3(DMODEL / 64, MT2), 256, 0, stream>>>(hb, w3t, out, tok, wg, offp);
}

// Round 4
// 860.230 us; speedup vs baseline: 1.2555x; 1.0072x over previous
//
#include <hip/hip_runtime.h>
#include <hip/hip_bf16.h>

typedef __attribute__((ext_vector_type(8))) short short8;
typedef __attribute__((ext_vector_type(4))) float f32x4;
typedef unsigned short u16;
typedef unsigned int u32;

#define NTOK   8192
#define DMODEL 1024
#define DFF    4096
#define NEXP   8
#define NPAIR  (NTOK * 2)
#define PADM   256            // per-expert padding (stage1 tile M)
#define MT1    72             // ceil((16384 + 8*255)/256)
#define PPAD   (MT1 * PADM)   // 18432
#define MT2    (PPAD / 128)   // 144 stage2 M-tiles

// ---- workspace layout (bytes) ----
#define OFF_XB   0ull
#define OFF_W1T  (OFF_XB  + (size_t)NTOK * DMODEL * 2)        //  16,777,216
#define OFF_W2T  (OFF_W1T + (size_t)NEXP * DFF * DMODEL * 2)  //  83,886,080
#define OFF_W3T  (OFF_W2T + (size_t)NEXP * DFF * DMODEL * 2)  // 150,994,944
#define OFF_H    (OFF_W3T + (size_t)NEXP * DMODEL * DFF * 2)  // 218,103,808
#define OFF_TOK  (OFF_H   + (size_t)PPAD * DFF * 2)           // 369,098,752
#define OFF_WGT  (OFF_TOK + (size_t)PPAD * 4)
#define OFF_CNT  (OFF_WGT + (size_t)PPAD * 4)
#define OFF_CUR  (OFF_CNT + 64)
#define OFF_OFFP (OFF_CUR + 64)
#define WS_END   (OFF_OFFP + 64)

#define GLOAD16(gp, lp)                                                        \
  __builtin_amdgcn_global_load_lds(                                            \
      (const __attribute__((address_space(1))) u32*)(gp),                      \
      (__attribute__((address_space(3))) u32*)(lp), 16, 0, 0)

__device__ __forceinline__ u16 f2bu(float f) {
  __hip_bfloat16 b = __float2bfloat16(f);
  return __builtin_bit_cast(u16, b);
}

// ---------------- conversion kernels ----------------

__global__ __launch_bounds__(256) void cvt_x_k(const float* __restrict__ x,
                                               u16* __restrict__ xb) {
  int i = blockIdx.x * 256 + threadIdx.x;
  float4 v = ((const float4*)x)[i];
  unsigned long long pk = (unsigned long long)f2bu(v.x) |
                          ((unsigned long long)f2bu(v.y) << 16) |
                          ((unsigned long long)f2bu(v.z) << 32) |
                          ((unsigned long long)f2bu(v.w) << 48);
  ((unsigned long long*)xb)[i] = pk;
}

// transpose [R][C] fp32 -> [C][R] bf16, batched over blockIdx.z
__global__ __launch_bounds__(256) void tr_cvt_k(const float* __restrict__ src,
                                                u16* __restrict__ dst, int R, int C) {
  src += (size_t)blockIdx.z * R * C;
  dst += (size_t)blockIdx.z * R * C;
  int c0 = blockIdx.x * 64, r0 = blockIdx.y * 64;
  __shared__ float tile[64][65];
  int tid = threadIdx.x;
  int f4 = tid & 15, rr = tid >> 4;
#pragma unroll
  for (int p = 0; p < 4; ++p) {
    int r = rr + p * 16;
    float4 v = *(const float4*)(src + (size_t)(r0 + r) * C + c0 + f4 * 4);
    tile[r][f4 * 4 + 0] = v.x; tile[r][f4 * 4 + 1] = v.y;
    tile[r][f4 * 4 + 2] = v.z; tile[r][f4 * 4 + 3] = v.w;
  }
  __syncthreads();
  int ch = tid & 7, cc = tid >> 3;
#pragma unroll
  for (int p = 0; p < 2; ++p) {
    int c = cc + p * 32;
    short8 s;
#pragma unroll
    for (int j = 0; j < 8; ++j) s[j] = (short)f2bu(tile[ch * 8 + j][c]);
    *(short8*)(dst + (size_t)(c0 + c) * R + r0 + ch * 8) = s;
  }
}

// ---------------- routing kernels ----------------

__global__ __launch_bounds__(256) void count_k(const int* __restrict__ ei,
                                               int* __restrict__ cnt) {
  int i = blockIdx.x * 256 + threadIdx.x;
  atomicAdd(&cnt[ei[i]], 1);
}

__global__ void scan_k(const int* __restrict__ cnt, int* __restrict__ offp) {
  if (threadIdx.x == 0) {
    int a = 0;
#pragma unroll
    for (int e = 0; e < NEXP; ++e) { offp[e] = a; a += (cnt[e] + PADM - 1) & ~(PADM - 1); }
    offp[NEXP] = a;
  }
}

__global__ __launch_bounds__(256) void scatter_k(const int* __restrict__ ei,
                                                 const float* __restrict__ ew,
                                                 const int* __restrict__ offp,
                                                 int* __restrict__ cur,
                                                 int* __restrict__ tok,
                                                 float* __restrict__ wg) {
  int i = blockIdx.x * 256 + threadIdx.x;
  int e = ei[i];
  int p = offp[e] + atomicAdd(&cur[e], 1);
  tok[p] = i >> 1;
  wg[p] = ew[i];
}

// ---------------- stage 1: h = silu(x@W1) * (x@W2), grouped ----------------
// 3-phase schedule per K-step: all 8 next-step global_load_lds issued in P0
// (so the end-of-step vmcnt(0) drain waits on loads issued ~2 phases / >1500cy
// earlier -> covered); P2 merges the two trailing MFMA quadrants (32-MFMA
// cluster, bf1/bf2 held in regs). 6 barriers/step (was 9).

#define A_STR 16384   // u16 per A buffer (256*64)
#define B_STR 8192    // u16 per B buffer (128*64)

__global__ __launch_bounds__(512, 2) void stage1_k(const u16* __restrict__ xb,
                                                   const u16* __restrict__ w1t,
                                                   const u16* __restrict__ w2t,
                                                   u16* __restrict__ h,
                                                   const int* __restrict__ tok,
                                                   const int* __restrict__ offp) {
  extern __shared__ __align__(16) u16 lds[];   // [2*A | 2*B1 | 2*B2] = 131072 B
  const int r0 = blockIdx.y * PADM;
  if (r0 >= offp[NEXP]) return;
  int e = 0;
#pragma unroll
  for (int q = 0; q < 7; ++q) e += (offp[e + 1] <= r0) ? 1 : 0;
  const int n0 = blockIdx.x * 128;
  const int tid = threadIdx.x;
  const int lane = tid & 63, w = tid >> 6;
  const int wm = w >> 2, wn = w & 3;
  const int lr = lane >> 3, seg = lane & 7;

  // ---- staging source pointers (per-lane, source-side XOR swizzle) ----
  const u16* aga[4];
  int adb[4];
#pragma unroll
  for (int u = 0; u < 2; ++u)
#pragma unroll
    for (int j = 0; j < 2; ++j) {
      int row = u * 128 + w * 16 + j * 8 + lr;
      int t = tok[r0 + row];
      aga[u * 2 + j] = xb + (size_t)t * DMODEL + ((seg ^ (row & 7)) << 3);
      adb[u * 2 + j] = (u * 128 + w * 16 + j * 8) * 64;
    }
  const u16* w1e = w1t + (size_t)e * DFF * DMODEL;
  const u16* w2e = w2t + (size_t)e * DFF * DMODEL;
  const u16* bg1[2]; const u16* bg2[2];
  int bdb[2];
#pragma unroll
  for (int j = 0; j < 2; ++j) {
    int row = w * 16 + j * 8 + lr;               // B tile row = ff-col offset
    size_t ro = (size_t)(n0 + row) * DMODEL + ((seg ^ (row & 7)) << 3);
    bg1[j] = w1e + ro; bg2[j] = w2e + ro;
    bdb[j] = (w * 16 + j * 8) * 64;
  }

  // ---- fragment read offsets (u16 idx; kk=1 = kk=0 XOR 32) ----
  int aoff[8], boff[2];
  {
    int ks = lane >> 4;
#pragma unroll
    for (int mi = 0; mi < 8; ++mi) {
      int row = wm * 128 + mi * 16 + (lane & 15);
      aoff[mi] = row * 64 + ((ks ^ (row & 7)) << 3);
    }
#pragma unroll
    for (int ni = 0; ni < 2; ++ni) {
      int col = wn * 32 + ni * 16 + (lane & 15);
      boff[ni] = col * 64 + ((ks ^ (col & 7)) << 3);
    }
  }

  f32x4 accg[8][2], accv[8][2];
  const f32x4 zero = {0.f, 0.f, 0.f, 0.f};
#pragma unroll
  for (int mi = 0; mi < 8; ++mi)
#pragma unroll
    for (int ni = 0; ni < 2; ++ni) { accg[mi][ni] = zero; accv[mi][ni] = zero; }

  short8 af[4][2], bf1[2][2], bf2[2][2];

  // ---- prologue: stage K-step 0 into buffer 0 ----
  {
    u16* Aq = lds; u16* B1q = lds + 2 * A_STR; u16* B2q = lds + 2 * A_STR + 2 * B_STR;
#pragma unroll
    for (int j = 0; j < 4; ++j) GLOAD16(aga[j], Aq + adb[j]);
#pragma unroll
    for (int j = 0; j < 2; ++j) { GLOAD16(bg1[j], B1q + bdb[j]);
                                  GLOAD16(bg2[j], B2q + bdb[j]); }
    asm volatile("s_waitcnt vmcnt(0)" ::: "memory");
    __builtin_amdgcn_s_barrier();
    __builtin_amdgcn_sched_barrier(0);
  }

#define S1_STEP(P, KC)                                                         \
  {                                                                            \
    const u16* Ab  = lds + (P) * A_STR;                                        \
    const u16* B1b = lds + 2 * A_STR + (P) * B_STR;                            \
    const u16* B2b = lds + 2 * A_STR + 2 * B_STR + (P) * B_STR;                \
    u16* Aq  = lds + (1 - (P)) * A_STR;                                        \
    u16* B1q = lds + 2 * A_STR + (1 - (P)) * B_STR;                            \
    u16* B2q = lds + 2 * A_STR + 2 * B_STR + (1 - (P)) * B_STR;                \
    const int st = (KC) + 1 < 16;                                              \
    const int ko = ((KC) + 1) * 64;                                            \
    /* ---- P0: read a[0:3]+b1; issue ALL 8 next-step loads; mfma g[0:3] */    \
    _Pragma("unroll") for (int mi = 0; mi < 4; ++mi)                           \
      _Pragma("unroll") for (int kk = 0; kk < 2; ++kk)                         \
        af[mi][kk] = *(const short8*)(Ab + (aoff[mi] ^ (kk << 5)));            \
    _Pragma("unroll") for (int ni = 0; ni < 2; ++ni)                           \
      _Pragma("unroll") for (int kk = 0; kk < 2; ++kk)                         \
        bf1[ni][kk] = *(const short8*)(B1b + (boff[ni] ^ (kk << 5)));          \
    if (st) {                                                                  \
      _Pragma("unroll") for (int j = 0; j < 4; ++j)                            \
        GLOAD16(aga[j] + ko, Aq + adb[j]);                                     \
      _Pragma("unroll") for (int j = 0; j < 2; ++j) {                          \
        GLOAD16(bg1[j] + ko, B1q + bdb[j]);                                    \
        GLOAD16(bg2[j] + ko, B2q + bdb[j]);                                    \
      }                                                                        \
    }                                                                          \
    __builtin_amdgcn_s_barrier();                                              \
    __builtin_amdgcn_s_setprio(1);                                             \
    _Pragma("unroll") for (int mi = 0; mi < 4; ++mi)                           \
      _Pragma("unroll") for (int ni = 0; ni < 2; ++ni)                         \
        _Pragma("unroll") for (int kk = 0; kk < 2; ++kk)                       \
          accg[mi][ni] = __builtin_amdgcn_mfma_f32_16x16x32_bf16(              \
              af[mi][kk], bf1[ni][kk], accg[mi][ni], 0, 0, 0);                 \
    __builtin_amdgcn_s_setprio(0);                                             \
    __builtin_amdgcn_s_barrier();                                              \
    /* ---- P1: read b2; mfma v[0:3] ---- */                                   \
    _Pragma("unroll") for (int ni = 0; ni < 2; ++ni)                           \
      _Pragma("unroll") for (int kk = 0; kk < 2; ++kk)                         \
        bf2[ni][kk] = *(const short8*)(B2b + (boff[ni] ^ (kk << 5)));          \
    __builtin_amdgcn_s_barrier();                                              \
    __builtin_amdgcn_s_setprio(1);                                             \
    _Pragma("unroll") for (int mi = 0; mi < 4; ++mi)                           \
      _Pragma("unroll") for (int ni = 0; ni < 2; ++ni)                         \
        _Pragma("unroll") for (int kk = 0; kk < 2; ++kk)                       \
          accv[mi][ni] = __builtin_amdgcn_mfma_f32_16x16x32_bf16(              \
              af[mi][kk], bf2[ni][kk], accv[mi][ni], 0, 0, 0);                 \
    __builtin_amdgcn_s_setprio(0);                                             \
    __builtin_amdgcn_s_barrier();                                              \
    /* ---- P2: read a[4:7]; mfma g[4:7]+v[4:7] (bf1/bf2 held); drain ---- */  \
    _Pragma("unroll") for (int mi = 0; mi < 4; ++mi)                           \
      _Pragma("unroll") for (int kk = 0; kk < 2; ++kk)                         \
        af[mi][kk] = *(const short8*)(Ab + (aoff[4 + mi] ^ (kk << 5)));        \
    __builtin_amdgcn_s_barrier();                                              \
    __builtin_amdgcn_s_setprio(1);                                             \
    _Pragma("unroll") for (int mi = 0; mi < 4; ++mi)                           \
      _Pragma("unroll") for (int ni = 0; ni < 2; ++ni)                         \
        _Pragma("unroll") for (int kk = 0; kk < 2; ++kk)                       \
          accg[4 + mi][ni] = __builtin_amdgcn_mfma_f32_16x16x32_bf16(          \
              af[mi][kk], bf1[ni][kk], accg[4 + mi][ni], 0, 0, 0);             \
    _Pragma("unroll") for (int mi = 0; mi < 4; ++mi)                           \
      _Pragma("unroll") for (int ni = 0; ni < 2; ++ni)                         \
        _Pragma("unroll") for (int kk = 0; kk < 2; ++kk)                       \
          accv[4 + mi][ni] = __builtin_amdgcn_mfma_f32_16x16x32_bf16(          \
              af[mi][kk], bf2[ni][kk], accv[4 + mi][ni], 0, 0, 0);             \
    __builtin_amdgcn_s_setprio(0);                                             \
    asm volatile("s_waitcnt vmcnt(0)" ::: "memory");                           \
    __builtin_amdgcn_s_barrier();                                              \
    __builtin_amdgcn_sched_barrier(0);                                         \
  }

  for (int kc = 0; kc < 16; kc += 2) {
    S1_STEP(0, kc)
    S1_STEP(1, kc + 1)
  }
#undef S1_STEP

  // ---- epilogue: silu(gate) * val -> h ----
  const int prow = r0 + wm * 128 + ((lane >> 4) << 2);
  const int pcol = n0 + wn * 32 + (lane & 15);
#pragma unroll
  for (int mi = 0; mi < 8; ++mi)
#pragma unroll
    for (int ni = 0; ni < 2; ++ni)
#pragma unroll
      for (int j = 0; j < 4; ++j) {
        float g = accg[mi][ni][j];
        float v = accv[mi][ni][j];
        float s = g / (1.f + __expf(-g));
        h[(size_t)(prow + mi * 16 + j) * DFF + (pcol + ni * 16)] = f2bu(s * v);
      }
}

// ---------------- stage 2: out += p * (h @ W3), grouped ----------------
// round-1 structure (known good): 256 thr, 128x64 tile, single-buffered LDS.

__global__ __launch_bounds__(256) void stage2_k(const u16* __restrict__ h,
                                                const u16* __restrict__ w3t,
                                                float* __restrict__ out,
                                                const int* __restrict__ tok,
                                                const float* __restrict__ wg,
                                                const int* __restrict__ offp) {
  __shared__ __align__(16) u16 As[128 * 64];
  __shared__ __align__(16) u16 Bs[64 * 64];
  const int r0 = blockIdx.y * 128;
  if (r0 >= offp[NEXP]) return;
  int e = 0;
#pragma unroll
  for (int q = 0; q < 7; ++q) e += (offp[e + 1] <= r0) ? 1 : 0;
  const int n0 = blockIdx.x * 64;
  const int tid = threadIdx.x;
  const int lane = tid & 63, w = tid >> 6;
  const int wm = w >> 1, wn = w & 1;
  const int lr = lane >> 3, seg = lane & 7;

  const u16* aga[4];
#pragma unroll
  for (int j = 0; j < 4; ++j) {
    int rowl = w * 32 + j * 8 + lr;
    aga[j] = h + (size_t)(r0 + rowl) * DFF + ((seg ^ (rowl & 7)) << 3);
  }
  const u16* w3e = w3t + (size_t)e * DMODEL * DFF;
  const u16* bga[2];
#pragma unroll
  for (int j = 0; j < 2; ++j) {
    int coll = w * 16 + j * 8 + lr;
    bga[j] = w3e + (size_t)(n0 + coll) * DFF + ((seg ^ (coll & 7)) << 3);
  }
  u16 *Ad[4], *Bd[2];
#pragma unroll
  for (int j = 0; j < 4; ++j) Ad[j] = As + (w * 32 + j * 8) * 64;
#pragma unroll
  for (int j = 0; j < 2; ++j) Bd[j] = Bs + (w * 16 + j * 8) * 64;

  int aoff[4][2], boff[2][2];
  {
    int ar = wm * 64 + (lane & 15), ks = lane >> 4;
#pragma unroll
    for (int mi = 0; mi < 4; ++mi)
#pragma unroll
      for (int kk = 0; kk < 2; ++kk) {
        int row = ar + mi * 16;
        aoff[mi][kk] = row * 64 + (((kk * 4 + ks) ^ (row & 7)) << 3);
      }
    int bc = wn * 32 + (lane & 15);
#pragma unroll
    for (int ni = 0; ni < 2; ++ni)
#pragma unroll
      for (int kk = 0; kk < 2; ++kk) {
        int col = bc + ni * 16;
        boff[ni][kk] = col * 64 + (((kk * 4 + ks) ^ (col & 7)) << 3);
      }
  }

  f32x4 acc[4][2];
  const f32x4 zero = {0.f, 0.f, 0.f, 0.f};
#pragma unroll
  for (int mi = 0; mi < 4; ++mi)
#pragma unroll
    for (int ni = 0; ni < 2; ++ni) acc[mi][ni] = zero;

  for (int kc = 0; kc < DFF / 64; ++kc) {
    const int ko = kc * 64;
#pragma unroll
    for (int j = 0; j < 4; ++j) GLOAD16(aga[j] + ko, Ad[j]);
#pragma unroll
    for (int j = 0; j < 2; ++j) GLOAD16(bga[j] + ko, Bd[j]);
    __syncthreads();
#pragma unroll
    for (int kk = 0; kk < 2; ++kk) {
      short8 a[4], b[2];
#pragma unroll
      for (int mi = 0; mi < 4; ++mi) a[mi] = *(const short8*)(As + aoff[mi][kk]);
#pragma unroll
      for (int ni = 0; ni < 2; ++ni) b[ni] = *(const short8*)(Bs + boff[ni][kk]);
#pragma unroll
      for (int mi = 0; mi < 4; ++mi)
#pragma unroll
        for (int ni = 0; ni < 2; ++ni)
          acc[mi][ni] = __builtin_amdgcn_mfma_f32_16x16x32_bf16(a[mi], b[ni], acc[mi][ni], 0, 0, 0);
    }
    __syncthreads();
  }

  const int prow = r0 + wm * 64 + ((lane >> 4) << 2);
  const int pcol = n0 + wn * 32 + (lane & 15);
#pragma unroll
  for (int mi = 0; mi < 4; ++mi)
#pragma unroll
    for (int j = 0; j < 4; ++j) {
      int pos = prow + mi * 16 + j;
      float p = wg[pos];
      if (p != 0.f) {
        int t = tok[pos];
#pragma unroll
        for (int ni = 0; ni < 2; ++ni)
          atomicAdd(&out[(size_t)t * DMODEL + pcol + ni * 16], p * acc[mi][ni][j]);
      }
    }
}

// ---------------- launch ----------------

extern "C" void kernel_launch(void* const* d_in, const int* in_sizes, int n_in,
                              void* d_out, int out_size, void* d_ws, size_t ws_size,
                              hipStream_t stream) {
  (void)in_sizes; (void)n_in;
  const float* x  = (const float*)d_in[0];
  const int*   ei = (const int*)d_in[1];
  const float* ew = (const float*)d_in[2];
  const float* w1 = (const float*)d_in[3];
  const float* w2 = (const float*)d_in[4];
  const float* w3 = (const float*)d_in[5];
  float* out = (float*)d_out;
  char* ws = (char*)d_ws;

  hipMemsetAsync(out, 0, (size_t)out_size * sizeof(float), stream);
  if (ws_size < WS_END) return;   // ws too small: leave zeros (diagnosable absmax)

  u16* xb   = (u16*)(ws + OFF_XB);
  u16* w1t  = (u16*)(ws + OFF_W1T);
  u16* w2t  = (u16*)(ws + OFF_W2T);
  u16* w3t  = (u16*)(ws + OFF_W3T);
  u16* hb   = (u16*)(ws + OFF_H);
  int* tok  = (int*)(ws + OFF_TOK);
  float* wg = (float*)(ws + OFF_WGT);
  int* cnt  = (int*)(ws + OFF_CNT);
  int* cur  = (int*)(ws + OFF_CUR);
  int* offp = (int*)(ws + OFF_OFFP);

  hipMemsetAsync(ws + OFF_TOK, 0, (size_t)(WS_END - OFF_TOK), stream);

  hipFuncSetAttribute(reinterpret_cast<const void*>(stage1_k),
                      hipFuncAttributeMaxDynamicSharedMemorySize, 131072);

  cvt_x_k<<<dim3(NTOK * DMODEL / 4 / 256), 256, 0, stream>>>(x, xb);
  tr_cvt_k<<<dim3(DFF / 64, DMODEL / 64, NEXP), 256, 0, stream>>>(w1, w1t, DMODEL, DFF);
  tr_cvt_k<<<dim3(DFF / 64, DMODEL / 64, NEXP), 256, 0, stream>>>(w2, w2t, DMODEL, DFF);
  tr_cvt_k<<<dim3(DMODEL / 64, DFF / 64, NEXP), 256, 0, stream>>>(w3, w3t, DFF, DMODEL);
  count_k<<<dim3(NPAIR / 256), 256, 0, stream>>>(ei, cnt);
  scan_k<<<1, 64, 0, stream>>>(cnt, offp);
  scatter_k<<<dim3(NPAIR / 256), 256, 0, stream>>>(ei, ew, offp, cur, tok, wg);
  stage1_k<<<dim3(DFF / 128, MT1), 512, 131072, stream>>>(xb, w1t, w2t, hb, tok, offp);
  stage2_k<<<dim3(DMODEL / 64, MT2), 256, 0, stream>>>(hb, w3t, out, tok, wg, offp);
}

// Round 5
// 842.503 us; speedup vs baseline: 1.2819x; 1.0210x over previous
//
#include <hip/hip_runtime.h>
#include <hip/hip_bf16.h>

typedef __attribute__((ext_vector_type(8))) short short8;
typedef __attribute__((ext_vector_type(4))) float f32x4;
typedef unsigned short u16;
typedef unsigned int u32;

#define NTOK   8192
#define DMODEL 1024
#define DFF    4096
#define NEXP   8
#define NPAIR  (NTOK * 2)
#define PADM   256            // per-expert padding (stage1 tile M)
#define MT1    72             // ceil((16384 + 8*255)/256)
#define PPAD   (MT1 * PADM)   // 18432
#define MT2    (PPAD / 128)   // 144 stage2 M-tiles

// ---- workspace layout (bytes) ----
#define OFF_XB   0ull
#define OFF_W1T  (OFF_XB  + (size_t)NTOK * DMODEL * 2)        //  16,777,216
#define OFF_W2T  (OFF_W1T + (size_t)NEXP * DFF * DMODEL * 2)  //  83,886,080
#define OFF_W3T  (OFF_W2T + (size_t)NEXP * DFF * DMODEL * 2)  // 150,994,944
#define OFF_H    (OFF_W3T + (size_t)NEXP * DMODEL * DFF * 2)  // 218,103,808
#define OFF_TOK  (OFF_H   + (size_t)PPAD * DFF * 2)           // 369,098,752
#define OFF_WGT  (OFF_TOK + (size_t)PPAD * 4)
#define OFF_CNT  (OFF_WGT + (size_t)PPAD * 4)
#define OFF_CUR  (OFF_CNT + 64)
#define OFF_OFFP (OFF_CUR + 64)
#define WS_END   (OFF_OFFP + 64)

#define GLOAD16(gp, lp)                                                        \
  __builtin_amdgcn_global_load_lds(                                            \
      (const __attribute__((address_space(1))) u32*)(gp),                      \
      (__attribute__((address_space(3))) u32*)(lp), 16, 0, 0)

__device__ __forceinline__ u16 f2bu(float f) {
  __hip_bfloat16 b = __float2bfloat16(f);
  return __builtin_bit_cast(u16, b);
}

// ---------------- conversion kernels ----------------

__global__ __launch_bounds__(256) void cvt_x_k(const float* __restrict__ x,
                                               u16* __restrict__ xb) {
  int i = blockIdx.x * 256 + threadIdx.x;
  float4 v = ((const float4*)x)[i];
  unsigned long long pk = (unsigned long long)f2bu(v.x) |
                          ((unsigned long long)f2bu(v.y) << 16) |
                          ((unsigned long long)f2bu(v.z) << 32) |
                          ((unsigned long long)f2bu(v.w) << 48);
  ((unsigned long long*)xb)[i] = pk;
}

// transpose [R][C] fp32 -> [C][R] bf16, batched over blockIdx.z
__global__ __launch_bounds__(256) void tr_cvt_k(const float* __restrict__ src,
                                                u16* __restrict__ dst, int R, int C) {
  src += (size_t)blockIdx.z * R * C;
  dst += (size_t)blockIdx.z * R * C;
  int c0 = blockIdx.x * 64, r0 = blockIdx.y * 64;
  __shared__ float tile[64][65];
  int tid = threadIdx.x;
  int f4 = tid & 15, rr = tid >> 4;
#pragma unroll
  for (int p = 0; p < 4; ++p) {
    int r = rr + p * 16;
    float4 v = *(const float4*)(src + (size_t)(r0 + r) * C + c0 + f4 * 4);
    tile[r][f4 * 4 + 0] = v.x; tile[r][f4 * 4 + 1] = v.y;
    tile[r][f4 * 4 + 2] = v.z; tile[r][f4 * 4 + 3] = v.w;
  }
  __syncthreads();
  int ch = tid & 7, cc = tid >> 3;
#pragma unroll
  for (int p = 0; p < 2; ++p) {
    int c = cc + p * 32;
    short8 s;
#pragma unroll
    for (int j = 0; j < 8; ++j) s[j] = (short)f2bu(tile[ch * 8 + j][c]);
    *(short8*)(dst + (size_t)(c0 + c) * R + r0 + ch * 8) = s;
  }
}

// ---------------- routing kernels ----------------

__global__ __launch_bounds__(256) void count_k(const int* __restrict__ ei,
                                               int* __restrict__ cnt) {
  int i = blockIdx.x * 256 + threadIdx.x;
  atomicAdd(&cnt[ei[i]], 1);
}

__global__ void scan_k(const int* __restrict__ cnt, int* __restrict__ offp) {
  if (threadIdx.x == 0) {
    int a = 0;
#pragma unroll
    for (int e = 0; e < NEXP; ++e) { offp[e] = a; a += (cnt[e] + PADM - 1) & ~(PADM - 1); }
    offp[NEXP] = a;
  }
}

__global__ __launch_bounds__(256) void scatter_k(const int* __restrict__ ei,
                                                 const float* __restrict__ ew,
                                                 const int* __restrict__ offp,
                                                 int* __restrict__ cur,
                                                 int* __restrict__ tok,
                                                 float* __restrict__ wg) {
  int i = blockIdx.x * 256 + threadIdx.x;
  int e = ei[i];
  int p = offp[e] + atomicAdd(&cur[e], 1);
  tok[p] = i >> 1;
  wg[p] = ew[i];
}

// ---------------- stage 1: h = silu(x@W1) * (x@W2), grouped ----------------
// 3-buffer pipeline, BK=32, tile 256x128, 512 thr (8 waves, 2M x 4N).
// Per K-step: 12 ds_read_b128 + 32 MFMA + 4 global_load_lds (for step s+2)
// + s_waitcnt vmcnt(4) (waits only loads for s+1; just-issued stay in
// flight) + ONE s_barrier. vmcnt never drains to 0 in the main loop.
// Buffer audit: step t reads buf(t%3), load-targets buf((t+2)%3); that
// buffer's last reads were step t-1 (barrier-separated). Per-wave vmcnt
// BEFORE the barrier => after barrier, next buffer valid for all waves.

#define S1_BUF 16384   // u16 per buffer: A 8192 | B1 4096 | B2 4096
#define S1_NK  32      // 1024 / 32

__global__ __launch_bounds__(512, 2) void stage1_k(const u16* __restrict__ xb,
                                                   const u16* __restrict__ w1t,
                                                   const u16* __restrict__ w2t,
                                                   u16* __restrict__ h,
                                                   const int* __restrict__ tok,
                                                   const int* __restrict__ offp) {
  extern __shared__ __align__(16) u16 lds[];   // 3 * 32 KB = 98304 B
  const int r0 = blockIdx.y * PADM;
  if (r0 >= offp[NEXP]) return;
  int e = 0;
#pragma unroll
  for (int q = 0; q < 7; ++q) e += (offp[e + 1] <= r0) ? 1 : 0;
  const int n0 = blockIdx.x * 128;
  const int tid = threadIdx.x;
  const int lane = tid & 63, w = tid >> 6;
  const int wm = w >> 2, wn = w & 3;

  // ---- staging source pointers (per-lane; source-side swizzle slot->kgroup)
  // row has 4 slots of 8 elems; slot s holds k-group (s ^ ((row>>1)&3)).
  const int sl = lane & 3, rl = lane >> 2;
  const u16* aga[2];
  int adb[2];
#pragma unroll
  for (int j = 0; j < 2; ++j) {
    int row = w * 32 + j * 16 + rl;
    int t = tok[r0 + row];
    aga[j] = xb + (size_t)t * DMODEL + ((sl ^ ((row >> 1) & 3)) << 3);
    adb[j] = (w * 32 + j * 16) * 32;
  }
  const u16* w1e = w1t + (size_t)e * DFF * DMODEL;
  const u16* w2e = w2t + (size_t)e * DFF * DMODEL;
  const u16* bg1; const u16* bg2;
  int bdb;
  {
    int row = w * 16 + rl;                       // B tile row = ff-col offset
    size_t ro = (size_t)(n0 + row) * DMODEL + ((sl ^ ((row >> 1) & 3)) << 3);
    bg1 = w1e + ro; bg2 = w2e + ro;
    bdb = (w * 16) * 32;
  }

  // ---- fragment read offsets (u16 idx). k-group ks lives at slot
  // ks ^ ((row>>1)&3)  -> 2-way bank aliasing only (free).
  int aoff[8], boff[2];
  {
    int ks = lane >> 4;
#pragma unroll
    for (int mi = 0; mi < 8; ++mi) {
      int row = wm * 128 + mi * 16 + (lane & 15);
      aoff[mi] = row * 32 + ((ks ^ ((row >> 1) & 3)) << 3);
    }
#pragma unroll
    for (int ni = 0; ni < 2; ++ni) {
      int col = wn * 32 + ni * 16 + (lane & 15);
      boff[ni] = col * 32 + ((ks ^ ((col >> 1) & 3)) << 3);
    }
  }

  f32x4 accg[8][2], accv[8][2];
  const f32x4 zero = {0.f, 0.f, 0.f, 0.f};
#pragma unroll
  for (int mi = 0; mi < 8; ++mi)
#pragma unroll
    for (int ni = 0; ni < 2; ++ni) { accg[mi][ni] = zero; accv[mi][ni] = zero; }

#define S1_ISSUE(Q, KO)                                                        \
  do {                                                                         \
    GLOAD16(aga[0] + (KO), (Q) + adb[0]);                                      \
    GLOAD16(aga[1] + (KO), (Q) + adb[1]);                                      \
    GLOAD16(bg1 + (KO), (Q) + 8192 + bdb);                                     \
    GLOAD16(bg2 + (KO), (Q) + 12288 + bdb);                                    \
  } while (0)

  // ---- prologue: issue K-step 0 (buf0) and 1 (buf1); wait step 0 only ----
  S1_ISSUE(lds, 0);
  S1_ISSUE(lds + S1_BUF, 32);
  asm volatile("s_waitcnt vmcnt(4)" ::: "memory");
  __builtin_amdgcn_s_barrier();
  __builtin_amdgcn_sched_barrier(0);

#define S1_STEP(P, KC, ISSUE)                                                  \
  {                                                                            \
    const u16* Ab  = lds + (P) * S1_BUF;                                       \
    const u16* B1b = Ab + 8192;                                                \
    const u16* B2b = Ab + 12288;                                               \
    short8 af[8], b1f[2], b2f[2];                                              \
    _Pragma("unroll") for (int mi = 0; mi < 8; ++mi)                           \
      af[mi] = *(const short8*)(Ab + aoff[mi]);                                \
    _Pragma("unroll") for (int ni = 0; ni < 2; ++ni) {                         \
      b1f[ni] = *(const short8*)(B1b + boff[ni]);                              \
      b2f[ni] = *(const short8*)(B2b + boff[ni]);                              \
    }                                                                          \
    if (ISSUE) S1_ISSUE(lds + (((P) + 2) % 3) * S1_BUF, ((KC) + 2) * 32);      \
    __builtin_amdgcn_s_setprio(1);                                             \
    _Pragma("unroll") for (int mi = 0; mi < 8; ++mi)                           \
      _Pragma("unroll") for (int ni = 0; ni < 2; ++ni) {                       \
        accg[mi][ni] = __builtin_amdgcn_mfma_f32_16x16x32_bf16(                \
            af[mi], b1f[ni], accg[mi][ni], 0, 0, 0);                           \
        accv[mi][ni] = __builtin_amdgcn_mfma_f32_16x16x32_bf16(                \
            af[mi], b2f[ni], accv[mi][ni], 0, 0, 0);                           \
      }                                                                        \
    __builtin_amdgcn_s_setprio(0);                                             \
    if (ISSUE) asm volatile("s_waitcnt vmcnt(4)" ::: "memory");                \
    else       asm volatile("s_waitcnt vmcnt(0)" ::: "memory");                \
    __builtin_amdgcn_s_barrier();                                              \
    __builtin_amdgcn_sched_barrier(0);                                         \
  }

  for (int kc = 0; kc < S1_NK - 2; kc += 3) {
    S1_STEP(0, kc, 1)
    S1_STEP(1, kc + 1, 1)
    S1_STEP(2, kc + 2, 1)
  }
  // tail: steps 30 (buf0) and 31 (buf1), no further issues
  S1_STEP(0, S1_NK - 2, 0)
  S1_STEP(1, S1_NK - 1, 0)
#undef S1_STEP
#undef S1_ISSUE

  // ---- epilogue: silu(gate) * val -> h ----
  const int prow = r0 + wm * 128 + ((lane >> 4) << 2);
  const int pcol = n0 + wn * 32 + (lane & 15);
#pragma unroll
  for (int mi = 0; mi < 8; ++mi)
#pragma unroll
    for (int ni = 0; ni < 2; ++ni)
#pragma unroll
      for (int j = 0; j < 4; ++j) {
        float g = accg[mi][ni][j];
        float v = accv[mi][ni][j];
        float s = g / (1.f + __expf(-g));
        h[(size_t)(prow + mi * 16 + j) * DFF + (pcol + ni * 16)] = f2bu(s * v);
      }
}

// ---------------- stage 2: out += p * (h @ W3), grouped ----------------
// round-1 structure (known good): 256 thr, 128x64 tile, single-buffered LDS.

__global__ __launch_bounds__(256) void stage2_k(const u16* __restrict__ h,
                                                const u16* __restrict__ w3t,
                                                float* __restrict__ out,
                                                const int* __restrict__ tok,
                                                const float* __restrict__ wg,
                                                const int* __restrict__ offp) {
  __shared__ __align__(16) u16 As[128 * 64];
  __shared__ __align__(16) u16 Bs[64 * 64];
  const int r0 = blockIdx.y * 128;
  if (r0 >= offp[NEXP]) return;
  int e = 0;
#pragma unroll
  for (int q = 0; q < 7; ++q) e += (offp[e + 1] <= r0) ? 1 : 0;
  const int n0 = blockIdx.x * 64;
  const int tid = threadIdx.x;
  const int lane = tid & 63, w = tid >> 6;
  const int wm = w >> 1, wn = w & 1;
  const int lr = lane >> 3, seg = lane & 7;

  const u16* aga[4];
#pragma unroll
  for (int j = 0; j < 4; ++j) {
    int rowl = w * 32 + j * 8 + lr;
    aga[j] = h + (size_t)(r0 + rowl) * DFF + ((seg ^ (rowl & 7)) << 3);
  }
  const u16* w3e = w3t + (size_t)e * DMODEL * DFF;
  const u16* bga[2];
#pragma unroll
  for (int j = 0; j < 2; ++j) {
    int coll = w * 16 + j * 8 + lr;
    bga[j] = w3e + (size_t)(n0 + coll) * DFF + ((seg ^ (coll & 7)) << 3);
  }
  u16 *Ad[4], *Bd[2];
#pragma unroll
  for (int j = 0; j < 4; ++j) Ad[j] = As + (w * 32 + j * 8) * 64;
#pragma unroll
  for (int j = 0; j < 2; ++j) Bd[j] = Bs + (w * 16 + j * 8) * 64;

  int aoff[4][2], boff[2][2];
  {
    int ar = wm * 64 + (lane & 15), ks = lane >> 4;
#pragma unroll
    for (int mi = 0; mi < 4; ++mi)
#pragma unroll
      for (int kk = 0; kk < 2; ++kk) {
        int row = ar + mi * 16;
        aoff[mi][kk] = row * 64 + (((kk * 4 + ks) ^ (row & 7)) << 3);
      }
    int bc = wn * 32 + (lane & 15);
#pragma unroll
    for (int ni = 0; ni < 2; ++ni)
#pragma unroll
      for (int kk = 0; kk < 2; ++kk) {
        int col = bc + ni * 16;
        boff[ni][kk] = col * 64 + (((kk * 4 + ks) ^ (col & 7)) << 3);
      }
  }

  f32x4 acc[4][2];
  const f32x4 zero = {0.f, 0.f, 0.f, 0.f};
#pragma unroll
  for (int mi = 0; mi < 4; ++mi)
#pragma unroll
    for (int ni = 0; ni < 2; ++ni) acc[mi][ni] = zero;

  for (int kc = 0; kc < DFF / 64; ++kc) {
    const int ko = kc * 64;
#pragma unroll
    for (int j = 0; j < 4; ++j) GLOAD16(aga[j] + ko, Ad[j]);
#pragma unroll
    for (int j = 0; j < 2; ++j) GLOAD16(bga[j] + ko, Bd[j]);
    __syncthreads();
#pragma unroll
    for (int kk = 0; kk < 2; ++kk) {
      short8 a[4], b[2];
#pragma unroll
      for (int mi = 0; mi < 4; ++mi) a[mi] = *(const short8*)(As + aoff[mi][kk]);
#pragma unroll
      for (int ni = 0; ni < 2; ++ni) b[ni] = *(const short8*)(Bs + boff[ni][kk]);
#pragma unroll
      for (int mi = 0; mi < 4; ++mi)
#pragma unroll
        for (int ni = 0; ni < 2; ++ni)
          acc[mi][ni] = __builtin_amdgcn_mfma_f32_16x16x32_bf16(a[mi], b[ni], acc[mi][ni], 0, 0, 0);
    }
    __syncthreads();
  }

  const int prow = r0 + wm * 64 + ((lane >> 4) << 2);
  const int pcol = n0 + wn * 32 + (lane & 15);
#pragma unroll
  for (int mi = 0; mi < 4; ++mi)
#pragma unroll
    for (int j = 0; j < 4; ++j) {
      int pos = prow + mi * 16 + j;
      float p = wg[pos];
      if (p != 0.f) {
        int t = tok[pos];
#pragma unroll
        for (int ni = 0; ni < 2; ++ni)
          atomicAdd(&out[(size_t)t * DMODEL + pcol + ni * 16], p * acc[mi][ni][j]);
      }
    }
}

// ---------------- launch ----------------

extern "C" void kernel_launch(void* const* d_in, const int* in_sizes, int n_in,
                              void* d_out, int out_size, void* d_ws, size_t ws_size,
                              hipStream_t stream) {
  (void)in_sizes; (void)n_in;
  const float* x  = (const float*)d_in[0];
  const int*   ei = (const int*)d_in[1];
  const float* ew = (const float*)d_in[2];
  const float* w1 = (const float*)d_in[3];
  const float* w2 = (const float*)d_in[4];
  const float* w3 = (const float*)d_in[5];
  float* out = (float*)d_out;
  char* ws = (char*)d_ws;

  hipMemsetAsync(out, 0, (size_t)out_size * sizeof(float), stream);
  if (ws_size < WS_END) return;   // ws too small: leave zeros (diagnosable absmax)

  u16* xb   = (u16*)(ws + OFF_XB);
  u16* w1t  = (u16*)(ws + OFF_W1T);
  u16* w2t  = (u16*)(ws + OFF_W2T);
  u16* w3t  = (u16*)(ws + OFF_W3T);
  u16* hb   = (u16*)(ws + OFF_H);
  int* tok  = (int*)(ws + OFF_TOK);
  float* wg = (float*)(ws + OFF_WGT);
  int* cnt  = (int*)(ws + OFF_CNT);
  int* cur  = (int*)(ws + OFF_CUR);
  int* offp = (int*)(ws + OFF_OFFP);

  hipMemsetAsync(ws + OFF_TOK, 0, (size_t)(WS_END - OFF_TOK), stream);

  hipFuncSetAttribute(reinterpret_cast<const void*>(stage1_k),
                      hipFuncAttributeMaxDynamicSharedMemorySize, 98304);

  cvt_x_k<<<dim3(NTOK * DMODEL / 4 / 256), 256, 0, stream>>>(x, xb);
  tr_cvt_k<<<dim3(DFF / 64, DMODEL / 64, NEXP), 256, 0, stream>>>(w1, w1t, DMODEL, DFF);
  tr_cvt_k<<<dim3(DFF / 64, DMODEL / 64, NEXP), 256, 0, stream>>>(w2, w2t, DMODEL, DFF);
  tr_cvt_k<<<dim3(DMODEL / 64, DFF / 64, NEXP), 256, 0, stream>>>(w3, w3t, DFF, DMODEL);
  count_k<<<dim3(NPAIR / 256), 256, 0, stream>>>(ei, cnt);
  scan_k<<<1, 64, 0, stream>>>(cnt, offp);
  scatter_k<<<dim3(NPAIR / 256), 256, 0, stream>>>(ei, ew, offp, cur, tok, wg);
  stage1_k<<<dim3(DFF / 128, MT1), 512, 98304, stream>>>(xb, w1t, w2t, hb, tok, offp);
  stage2_k<<<dim3(DMODEL / 64, MT2), 256, 0, stream>>>(hb, w3t, out, tok, wg, offp);
}